// Round 13
// baseline (1593.301 us; speedup 1.0000x reference)
//
#include <hip/hip_runtime.h>
#include <hip/hip_bf16.h>

#define BB   16
#define TD   256
#define TE   1024
#define DM   512
#define DFF  2048
#define NL   6
#define NH   8
#define DH   64

typedef unsigned short u16;
typedef unsigned int u32;
typedef short short8 __attribute__((ext_vector_type(8)));
typedef float f32x4 __attribute__((ext_vector_type(4)));

__device__ __forceinline__ float b2f(u16 u) {
    unsigned int x = ((unsigned int)u) << 16;
    float f;
    __builtin_memcpy(&f, &x, 4);
    return f;
}
__device__ __forceinline__ u16 f2b(float f) {           // round-to-nearest-even
    unsigned int x;
    __builtin_memcpy(&x, &f, 4);
    unsigned int r = x + 0x7fffu + ((x >> 16) & 1u);
    return (u16)(r >> 16);
}

// async global->LDS, 16B per lane, LDS dest = wave-uniform base + lane*16
__device__ __forceinline__ void gload_lds16(const u16* g, u16* l) {
    __builtin_amdgcn_global_load_lds(
        (const __attribute__((address_space(1))) unsigned int*)g,
        (__attribute__((address_space(3))) unsigned int*)l, 16, 0, 0);
}

// ---------------- f32 -> bf16 bulk convert (enc) ----------------
__global__ __launch_bounds__(256) void cvt_kernel(const float* __restrict__ in,
                                                  u16* __restrict__ out, int n4) {
    int i = blockIdx.x * 256 + threadIdx.x;
    if (i < n4) {
        float4 v = reinterpret_cast<const float4*>(in)[i];
        ushort4 o;
        o.x = f2b(v.x); o.y = f2b(v.y); o.z = f2b(v.z); o.w = f2b(v.w);
        reinterpret_cast<ushort4*>(out)[i] = o;
    }
}

// ---------------- weight transpose+convert: W[K][N] f32 -> Wt[N][K] bf16 -------
template <int NMAT>
struct PtrArr { const float* p[NMAT]; };

template <int NMAT>
__global__ __launch_bounds__(256) void tr_kernel(PtrArr<NMAT> P, u16* __restrict__ out,
                                                 int K, int N) {
    __shared__ u16 t[64][65];
    const float* W = P.p[blockIdx.z];
    u16* O = out + (size_t)blockIdx.z * K * N;
    int n0 = blockIdx.x * 64, k0 = blockIdx.y * 64;
    int tid = threadIdx.x;
    int r = tid >> 4, c = (tid & 15) * 4;
#pragma unroll
    for (int p = 0; p < 4; ++p) {
        int k = r + p * 16;
        float4 v = *reinterpret_cast<const float4*>(&W[(size_t)(k0 + k) * N + n0 + c]);
        t[c + 0][k] = f2b(v.x);
        t[c + 1][k] = f2b(v.y);
        t[c + 2][k] = f2b(v.z);
        t[c + 3][k] = f2b(v.w);
    }
    __syncthreads();
#pragma unroll
    for (int p = 0; p < 4; ++p) {
        int n = r + p * 16;
        ushort4 o;
        o.x = t[n][c]; o.y = t[n][c + 1]; o.z = t[n][c + 2]; o.w = t[n][c + 3];
        *reinterpret_cast<ushort4*>(&O[(size_t)(n0 + n) * K + k0 + c]) = o;
    }
}

// ---------------- embedding + sinusoidal PE -> bf16 ----------------
__global__ __launch_bounds__(256) void embed_kernel(const int* __restrict__ targets,
                                                    const float* __restrict__ emb,
                                                    u16* __restrict__ out) {
    int row = blockIdx.x;
    int t   = row & (TD - 1);
    int tgt = targets[row];
    const float c = -0.017988946039015984f;   // -ln(10000)/512
    for (int d = threadIdx.x; d < DM; d += 256) {
        float e   = emb[(size_t)tgt * DM + d] * 22.627416997969522f;  // sqrt(512)
        int   i2  = d & ~1;
        float div = expf(c * (float)i2);
        float arg = (float)t * div;
        float pe  = (d & 1) ? cosf(arg) : sinf(arg);
        out[(size_t)row * DM + d] = f2b(e + pe);
    }
}

// ====== fused-LN helpers: per-block row stats (E[x^2]-mean^2, same as prior ln) =
template <int TM>
__device__ __forceinline__ void ln_stats(const float* __restrict__ Xf, int row0,
                                         float* sm_mean, float* sm_rstd, int tid) {
    constexpr int TPR = 256 / TM;          // threads per row (4 for TM=64, 2 for TM=128)
    constexpr int EPT = DM / TPR;          // elems per thread
    int lrow = tid / TPR, lseg = tid % TPR;
    const float* xr = Xf + (size_t)(row0 + lrow) * DM + lseg * EPT;
    float s = 0.f, sq = 0.f;
#pragma unroll 8
    for (int j = 0; j < EPT; j += 4) {
        float4 v = *reinterpret_cast<const float4*>(&xr[j]);
        s  += v.x + v.y + v.z + v.w;
        sq += v.x * v.x + v.y * v.y + v.z * v.z + v.w * v.w;
    }
#pragma unroll
    for (int off = 1; off < TPR; off <<= 1) {
        s  += __shfl_xor(s, off);
        sq += __shfl_xor(sq, off);
    }
    if (lseg == 0) {
        float mean = s * (1.0f / 512.0f);
        float var  = sq * (1.0f / 512.0f) - mean * mean;
        sm_mean[lrow] = mean;
        sm_rstd[lrow] = rsqrtf(var + 1e-5f);
    }
    __syncthreads();
}

// fused-LN A staging: f32 load -> normalize*gamma+beta -> bf16 ds_write_b128.
// Writes the EXACT layout gload_lds16 would produce ([row][32k], 16B/thread).
template <int TM>
__device__ __forceinline__ void stage_ln(const float* __restrict__ Xf,
                                         const float* __restrict__ lng,
                                         const float* __restrict__ lnb, size_t vo,
                                         int row0, int k0, u16* As,
                                         const float* sm_mean, const float* sm_rstd,
                                         int wave, int srow, int scol) {
#pragma unroll
    for (int s = 0; s < TM / 64; ++s) {
        int rbase = wave * (TM / 4) + s * 16;
        int row   = rbase + srow;
        float mean = sm_mean[row], rstd = sm_rstd[row];
        const float* xp = Xf + (size_t)(row0 + row) * DM + k0 + scol;
        float4 va = *reinterpret_cast<const float4*>(xp);
        float4 vb = *reinterpret_cast<const float4*>(xp + 4);
        const float* gp = lng + vo + k0 + scol;
        const float* bp = lnb + vo + k0 + scol;
        u16 t[8];
        t[0] = f2b((va.x - mean) * rstd * gp[0] + bp[0]);
        t[1] = f2b((va.y - mean) * rstd * gp[1] + bp[1]);
        t[2] = f2b((va.z - mean) * rstd * gp[2] + bp[2]);
        t[3] = f2b((va.w - mean) * rstd * gp[3] + bp[3]);
        t[4] = f2b((vb.x - mean) * rstd * gp[4] + bp[4]);
        t[5] = f2b((vb.y - mean) * rstd * gp[5] + bp[5]);
        t[6] = f2b((vb.z - mean) * rstd * gp[6] + bp[6]);
        t[7] = f2b((vb.w - mean) * rstd * gp[7] + bp[7]);
        __builtin_memcpy(&As[(size_t)(rbase + srow) * 32 + scol], t, 16);
    }
}

// ---------------- 2-phase double-buffered GEMM (optional fused-LN A path) -------
// C = act(A[MxK] @ Wt[NxK]^T + bias) (+resid). BK=32, LDS dbuf, prefetch-before-
// compute, ONE barrier per K-step. LNA: A comes from f32 Xf with fused layernorm
// (requires K==DM==512).
template <int TM, int TN, bool OUTBF, bool RELU, bool RES, bool LNA>
__global__ __launch_bounds__(256) void gemm_bt(const u16* __restrict__ A,
                                               const float* __restrict__ Xf,
                                               const float* __restrict__ lng,
                                               const float* __restrict__ lnb, size_t vo,
                                               const u16* __restrict__ Bt,
                                               const float* __restrict__ bias, size_t bofs,
                                               const float* __restrict__ resid,
                                               void* __restrict__ C,
                                               int M, int N, int K) {
    __shared__ u16 As[2][TM * 32];
    __shared__ u16 Bs[2][TN * 32];
    __shared__ float sm_mean[TM], sm_rstd[TM];
    int tid = threadIdx.x, wave = tid >> 6, lane = tid & 63;
    int col0 = blockIdx.x * TN, row0 = blockIdx.y * TM;
    constexpr int WM = TM / 2, WN = TN / 2;
    int wm = (wave >> 1) * WM, wn = (wave & 1) * WN;
    int lq = lane >> 4, lc = lane & 15;
    constexpr int NI = WM / 16, NJ = WN / 16;
    f32x4 acc[NI][NJ] = {};
    int srow = lane >> 2;          // 0..15 row within 16-row staging group
    int scol = (lane & 3) * 8;     // k element offset (8 bf16 = 16 B)

    if (LNA) ln_stats<TM>(Xf, row0, sm_mean, sm_rstd, tid);

    auto stage = [&](int buf, int k0) {
        if (LNA) {
            stage_ln<TM>(Xf, lng, lnb, vo, row0, k0, As[buf], sm_mean, sm_rstd,
                         wave, srow, scol);
        } else {
#pragma unroll
            for (int s = 0; s < TM / 64; ++s) {
                int rbase = wave * (TM / 4) + s * 16;
                gload_lds16(A + (size_t)(row0 + rbase + srow) * K + k0 + scol, &As[buf][rbase * 32]);
            }
        }
#pragma unroll
        for (int s = 0; s < TN / 64; ++s) {
            int rbase = wave * (TN / 4) + s * 16;
            gload_lds16(Bt + (size_t)(col0 + rbase + srow) * K + k0 + scol, &Bs[buf][rbase * 32]);
        }
    };

    stage(0, 0);
    __syncthreads();
    int cur = 0;
    for (int k0 = 0; k0 < K; k0 += 32) {
        if (k0 + 32 < K) stage(cur ^ 1, k0 + 32);   // prefetch next slice
        short8 af[NI], bf[NJ];
#pragma unroll
        for (int i = 0; i < NI; ++i)
            af[i] = *reinterpret_cast<const short8*>(&As[cur][(wm + i * 16 + lc) * 32 + lq * 8]);
#pragma unroll
        for (int j = 0; j < NJ; ++j)
            bf[j] = *reinterpret_cast<const short8*>(&Bs[cur][(wn + j * 16 + lc) * 32 + lq * 8]);
#pragma unroll
        for (int i = 0; i < NI; ++i)
#pragma unroll
            for (int j = 0; j < NJ; ++j)
                acc[i][j] = __builtin_amdgcn_mfma_f32_16x16x32_bf16(af[i], bf[j], acc[i][j], 0, 0, 0);
        __syncthreads();           // waits vmcnt(0)+lgkmcnt: staged tile landed
        cur ^= 1;
    }

    // epilogue: C/D layout col=lane&15, row=quad*4+reg
#pragma unroll
    for (int j = 0; j < NJ; ++j) {
        int n = col0 + wn + j * 16 + lc;
        float bv = bias[bofs + n];
#pragma unroll
        for (int i = 0; i < NI; ++i) {
#pragma unroll
            for (int r = 0; r < 4; ++r) {
                int m = row0 + wm + i * 16 + lq * 4 + r;
                float v = acc[i][j][r] + bv;
                if (RES)  v += resid[(size_t)m * N + n];
                if (RELU) v = fmaxf(v, 0.0f);
                if (OUTBF) ((u16*)C)[(size_t)m * N + n] = f2b(v);
                else       ((float*)C)[(size_t)m * N + n] = v;
            }
        }
    }
}

// ---------------- multi-group GEMM: concatenated-N weight, per-512-col group ----
// LNMODE: 0 = no fused LN; 1 = group 0 only (A = LN(Xf)); 2 = all groups.
// Optional lens-based M-tile skip per group (rows batched 1<<rbShift).
template <int NG>
struct MGrp {
    const u16* A[NG];
    u16* out[NG];
    const float* bias[NG];
    int mlim[NG];
    int skip[NG];
};

template <int TM, int TN, int NG, int LNMODE>
__global__ __launch_bounds__(256) void gemm_bt_multi(MGrp<NG> mg,
                                                     const float* __restrict__ Xf,
                                                     const float* __restrict__ lng,
                                                     const float* __restrict__ lnb, size_t vo,
                                                     const u16* __restrict__ Bt,
                                                     int K,
                                                     const int* __restrict__ lens,
                                                     int rbShift) {
    __shared__ u16 As[2][TM * 32];
    __shared__ u16 Bs[2][TN * 32];
    __shared__ float sm_mean[TM], sm_rstd[TM];
    int tid = threadIdx.x, wave = tid >> 6, lane = tid & 63;
    int col0 = blockIdx.x * TN, row0 = blockIdx.y * TM;
    int g  = col0 >> 9;            // block-uniform group select (512 % TN == 0)
    int c0 = col0 & 511;

    if (row0 >= mg.mlim[g]) return;
    if (mg.skip[g]) {
        int bb  = row0 >> rbShift;
        int rl  = row0 & ((1 << rbShift) - 1);
        int lim = (lens[bb] + 63) & ~63;
        if (rl >= lim) return;       // block-uniform: no barrier divergence
    }
    const u16* A = mg.A[g];
    bool useln = (LNMODE == 2) || (LNMODE == 1 && g == 0);

    constexpr int WM = TM / 2, WN = TN / 2;
    int wm = (wave >> 1) * WM, wn = (wave & 1) * WN;
    int lq = lane >> 4, lc = lane & 15;
    constexpr int NI = WM / 16, NJ = WN / 16;
    f32x4 acc[NI][NJ] = {};
    int srow = lane >> 2;
    int scol = (lane & 3) * 8;

    if (LNMODE && useln) ln_stats<TM>(Xf, row0, sm_mean, sm_rstd, tid);

    auto stage = [&](int buf, int k0) {
        if (LNMODE && useln) {
            stage_ln<TM>(Xf, lng, lnb, vo, row0, k0, As[buf], sm_mean, sm_rstd,
                         wave, srow, scol);
        } else {
#pragma unroll
            for (int s = 0; s < TM / 64; ++s) {
                int rbase = wave * (TM / 4) + s * 16;
                gload_lds16(A + (size_t)(row0 + rbase + srow) * K + k0 + scol, &As[buf][rbase * 32]);
            }
        }
#pragma unroll
        for (int s = 0; s < TN / 64; ++s) {
            int rbase = wave * (TN / 4) + s * 16;
            gload_lds16(Bt + (size_t)(col0 + rbase + srow) * K + k0 + scol, &Bs[buf][rbase * 32]);
        }
    };

    stage(0, 0);
    __syncthreads();
    int cur = 0;
    for (int k0 = 0; k0 < K; k0 += 32) {
        if (k0 + 32 < K) stage(cur ^ 1, k0 + 32);
        short8 af[NI], bf[NJ];
#pragma unroll
        for (int i = 0; i < NI; ++i)
            af[i] = *reinterpret_cast<const short8*>(&As[cur][(wm + i * 16 + lc) * 32 + lq * 8]);
#pragma unroll
        for (int j = 0; j < NJ; ++j)
            bf[j] = *reinterpret_cast<const short8*>(&Bs[cur][(wn + j * 16 + lc) * 32 + lq * 8]);
#pragma unroll
        for (int i = 0; i < NI; ++i)
#pragma unroll
            for (int j = 0; j < NJ; ++j)
                acc[i][j] = __builtin_amdgcn_mfma_f32_16x16x32_bf16(af[i], bf[j], acc[i][j], 0, 0, 0);
        __syncthreads();
        cur ^= 1;
    }

    u16* O = mg.out[g];
    const float* bp = mg.bias[g];
#pragma unroll
    for (int j = 0; j < NJ; ++j) {
        int n = c0 + wn + j * 16 + lc;
        float bv = bp[n];
#pragma unroll
        for (int i = 0; i < NI; ++i) {
#pragma unroll
            for (int r = 0; r < 4; ++r) {
                int m = row0 + wm + i * 16 + lq * 4 + r;
                O[(size_t)m * 512 + n] = f2b(acc[i][j][r] + bv);
            }
        }
    }
}

// ---------------- MFMA flash attention: fixed-max softmax, dbuf K/V ------------
// QBLK=64, 256 thr. p = exp(s - 8) (scores bounded), row-sum via ones-fragment
// MFMA. V pair-packed u32 in [64][32] + XOR swizzle. K/V LDS double-buffered:
// one barrier per KV tile. Maskless fast path off-diagonal/pre-len. s_setprio(1)
// around MFMA clusters. 1D grid, XCD-aware contiguous-chunk swizzle.
#define QSTR 72

__device__ __forceinline__ int vidx(int d, int kp) {
    return d * 32 + (kp ^ (((d >> 2) & 7) << 2));
}

__global__ __launch_bounds__(256) void fattn_mfma(const u16* __restrict__ Q,
                                                  const u16* __restrict__ K,
                                                  const u16* __restrict__ V,
                                                  const int* __restrict__ lens,
                                                  u16* __restrict__ O,
                                                  int Tq, int Tk, int causal) {
    __shared__ u16 Qs[64 * QSTR];
    __shared__ u16 Ks[2][64 * QSTR];
    __shared__ u16 Ps[64 * QSTR];
    __shared__ u32 Vs32[2][64 * 32];
    int tid  = threadIdx.x;
    int wg      = blockIdx.x;
    int chunk   = gridDim.x >> 3;                 // gridDim.x % 8 == 0 (bijective)
    int logical = (wg & 7) * chunk + (wg >> 3);
    int nq   = Tq / 64;                           // 4
    int b    = logical / (NH * nq);
    int rem  = logical - b * (NH * nq);
    int h    = rem / nq;
    int qt0  = (rem - h * nq) * 64;
    int len  = lens[b];
    int wave = tid >> 6, lane = tid & 63;
    int lq = lane >> 4, lc = lane & 15;
    int sr = tid >> 4;          // 0..15
    int sd = (tid & 15) * 4;

    short8 bones;
    {
        u16 v = (lc == 0) ? (u16)0x3F80 : (u16)0;
        u16 tmp[8] = { v, v, v, v, v, v, v, v };
        __builtin_memcpy(&bones, tmp, 16);
    }

    // Q tile load + scale (1/8 = 1/sqrt(dh))
#pragma unroll
    for (int i = 0; i < 4; ++i) {
        int q = sr + i * 16;
        ushort4 v = *reinterpret_cast<const ushort4*>(
            &Q[(size_t)(b * Tq + qt0 + q) * DM + h * DH + sd]);
        ushort4 w;
        w.x = f2b(b2f(v.x) * 0.125f); w.y = f2b(b2f(v.y) * 0.125f);
        w.z = f2b(b2f(v.z) * 0.125f); w.w = f2b(b2f(v.w) * 0.125f);
        *reinterpret_cast<ushort4*>(&Qs[q * QSTR + sd]) = w;
    }

    // K tile rows; V pair rows -> buf 0
    ushort4 kr[4], vr[2][2];
#pragma unroll
    for (int i = 0; i < 4; ++i) {
        int k = sr + i * 16;
        kr[i] = *reinterpret_cast<const ushort4*>(&K[(size_t)(b * Tk + k) * DM + h * DH + sd]);
    }
#pragma unroll
    for (int i = 0; i < 2; ++i) {
        int kp = sr + i * 16;
#pragma unroll
        for (int p = 0; p < 2; ++p)
            vr[i][p] = *reinterpret_cast<const ushort4*>(
                &V[(size_t)(b * Tk + 2 * kp + p) * DM + h * DH + sd]);
    }
#pragma unroll
    for (int i = 0; i < 4; ++i) {
        int k = sr + i * 16;
        *reinterpret_cast<ushort4*>(&Ks[0][k * QSTR + sd]) = kr[i];
    }
#pragma unroll
    for (int i = 0; i < 2; ++i) {
        int kp = sr + i * 16;
        u16 a0[4], a1[4];
        __builtin_memcpy(a0, &vr[i][0], 8);
        __builtin_memcpy(a1, &vr[i][1], 8);
#pragma unroll
        for (int j = 0; j < 4; ++j)
            Vs32[0][vidx(sd + j, kp)] = (u32)a0[j] | ((u32)a1[j] << 16);
    }
    __syncthreads();

    short8 aq0 = *reinterpret_cast<const short8*>(&Qs[(wave * 16 + lc) * QSTR + lq * 8]);
    short8 aq1 = *reinterpret_cast<const short8*>(&Qs[(wave * 16 + lc) * QSTR + 32 + lq * 8]);

    f32x4 Ow[4] = {};
    f32x4 Ol = {};

    int kend = causal ? min(len, qt0 + 64) : len;
    int cur = 0;
    for (int kt0 = 0; kt0 < kend; kt0 += 64) {
        bool more = (kt0 + 64) < kend;
        if (more) {
#pragma unroll
            for (int i = 0; i < 4; ++i) {
                int k = kt0 + 64 + sr + i * 16;
                kr[i] = *reinterpret_cast<const ushort4*>(
                    &K[(size_t)(b * Tk + k) * DM + h * DH + sd]);
            }
#pragma unroll
            for (int i = 0; i < 2; ++i) {
                int kp = sr + i * 16;
#pragma unroll
                for (int p = 0; p < 2; ++p)
                    vr[i][p] = *reinterpret_cast<const ushort4*>(
                        &V[(size_t)(b * Tk + kt0 + 64 + 2 * kp + p) * DM + h * DH + sd]);
            }
        }

        f32x4 sa[4] = {};
        __builtin_amdgcn_s_setprio(1);
#pragma unroll
        for (int n = 0; n < 4; ++n) {
            short8 bk0 = *reinterpret_cast<const short8*>(&Ks[cur][(n * 16 + lc) * QSTR + lq * 8]);
            short8 bk1 = *reinterpret_cast<const short8*>(&Ks[cur][(n * 16 + lc) * QSTR + 32 + lq * 8]);
            sa[n] = __builtin_amdgcn_mfma_f32_16x16x32_bf16(aq0, bk0, sa[n], 0, 0, 0);
            sa[n] = __builtin_amdgcn_mfma_f32_16x16x32_bf16(aq1, bk1, sa[n], 0, 0, 0);
        }
        __builtin_amdgcn_s_setprio(0);

        int qrow_base = qt0 + wave * 16 + lq * 4;
        bool nomask = (kt0 + 64 <= len) &&
                      (!causal || (kt0 + 63 <= qt0 + wave * 16));
        if (nomask) {
#pragma unroll
            for (int r = 0; r < 4; ++r)
#pragma unroll
                for (int n = 0; n < 4; ++n)
                    Ps[(wave * 16 + lq * 4 + r) * QSTR + n * 16 + lc] =
                        f2b(__expf(sa[n][r] - 8.0f));
        } else {
#pragma unroll
            for (int r = 0; r < 4; ++r) {
                int qrow = qrow_base + r;
#pragma unroll
                for (int n = 0; n < 4; ++n) {
                    int key = kt0 + n * 16 + lc;
                    bool inv = (key >= len) || (causal && key > qrow);
                    float p = inv ? 0.0f : __expf(sa[n][r] - 8.0f);
                    Ps[(wave * 16 + lq * 4 + r) * QSTR + n * 16 + lc] = f2b(p);
                }
            }
        }
        // no barrier: Ps rows [wave*16, wave*16+16) are wave-private

        short8 ap0 = *reinterpret_cast<const short8*>(&Ps[(wave * 16 + lc) * QSTR + lq * 8]);
        short8 ap1 = *reinterpret_cast<const short8*>(&Ps[(wave * 16 + lc) * QSTR + 32 + lq * 8]);
        __builtin_amdgcn_s_setprio(1);
#pragma unroll
        for (int n = 0; n < 4; ++n) {
            int d = n * 16 + lc;
#pragma unroll
            for (int ks = 0; ks < 2; ++ks) {
                int base = d * 32 + ((ks * 16 + lq * 4) ^ (((d >> 2) & 7) << 2));
                uint4 vv = *reinterpret_cast<const uint4*>(&Vs32[cur][base]);   // b128
                short8 bv;
                __builtin_memcpy(&bv, &vv, 16);
                Ow[n] = __builtin_amdgcn_mfma_f32_16x16x32_bf16(ks ? ap1 : ap0, bv, Ow[n], 0, 0, 0);
            }
        }
        Ol = __builtin_amdgcn_mfma_f32_16x16x32_bf16(ap0, bones, Ol, 0, 0, 0);
        Ol = __builtin_amdgcn_mfma_f32_16x16x32_bf16(ap1, bones, Ol, 0, 0, 0);
        __builtin_amdgcn_s_setprio(0);

        if (more) {
#pragma unroll
            for (int i = 0; i < 4; ++i) {
                int k = sr + i * 16;
                *reinterpret_cast<ushort4*>(&Ks[cur ^ 1][k * QSTR + sd]) = kr[i];
            }
#pragma unroll
            for (int i = 0; i < 2; ++i) {
                int kp = sr + i * 16;
                u16 a0[4], a1[4];
                __builtin_memcpy(a0, &vr[i][0], 8);
                __builtin_memcpy(a1, &vr[i][1], 8);
#pragma unroll
                for (int j = 0; j < 4; ++j)
                    Vs32[cur ^ 1][vidx(sd + j, kp)] = (u32)a0[j] | ((u32)a1[j] << 16);
            }
            __syncthreads();
            cur ^= 1;
        }
    }

#pragma unroll
    for (int r = 0; r < 4; ++r) {
        float lsum = __shfl(Ol[r], lane & 48);   // from lane lq*16 (lc==0)
        float inv = 1.0f / lsum;
        size_t rowoff = (size_t)(b * Tq + qt0 + wave * 16 + lq * 4 + r) * DM + h * DH;
#pragma unroll
        for (int n = 0; n < 4; ++n)
            O[rowoff + n * 16 + lc] = f2b(Ow[n][r] * inv);
    }
}

extern "C" void kernel_launch(void* const* d_in, const int* in_sizes, int n_in,
                              void* d_out, int out_size, void* d_ws, size_t ws_size,
                              hipStream_t stream) {
    const int*   targets = (const int*)d_in[0];
    const int*   tlen    = (const int*)d_in[1];
    const float* enc     = (const float*)d_in[2];
    const int*   elen    = (const int*)d_in[3];
    const float* emb     = (const float*)d_in[4];
    const float* W_in    = (const float*)d_in[5];
    const float* b_in    = (const float*)d_in[6];
    const float* ln1_g   = (const float*)d_in[7];
    const float* ln1_b   = (const float*)d_in[8];
    const float* Wq1 = (const float*)d_in[9],  *bq1 = (const float*)d_in[10];
    const float* Wk1 = (const float*)d_in[11], *bk1 = (const float*)d_in[12];
    const float* Wv1 = (const float*)d_in[13], *bv1 = (const float*)d_in[14];
    const float* Wo1 = (const float*)d_in[15], *bo1 = (const float*)d_in[16];
    const float* ln2_g = (const float*)d_in[17], *ln2_b = (const float*)d_in[18];
    const float* Wq2 = (const float*)d_in[19], *bq2 = (const float*)d_in[20];
    const float* Wk2 = (const float*)d_in[21], *bk2 = (const float*)d_in[22];
    const float* Wv2 = (const float*)d_in[23], *bv2 = (const float*)d_in[24];
    const float* Wo2 = (const float*)d_in[25], *bo2 = (const float*)d_in[26];
    const float* ln3_g = (const float*)d_in[27], *ln3_b = (const float*)d_in[28];
    const float* W_ff1 = (const float*)d_in[29], *b_ff1 = (const float*)d_in[30];
    const float* W_ff2 = (const float*)d_in[31], *b_ff2 = (const float*)d_in[32];

    float* ws   = (float*)d_ws;
    float* x    = ws;                              // 4096x512 f32
    u16*   hb   = (u16*)(ws + 2097152);            // 4096x512 bf16 (embed out)
    u16*   qb   = (u16*)(ws + 3145728);            // 4096x512 bf16
    u16*   ctx  = (u16*)(ws + 4194304);            // 4096x512 bf16
    u16*   kb   = (u16*)(ws + 5242880);            // 16384x512 bf16
    u16*   vb   = (u16*)(ws + 9437184);            // 16384x512 bf16
    u16*   encb = (u16*)(ws + 13631488);           // 16384x512 bf16
    u16*   wt_dm = (u16*)(ws + 17825792);          // 49 x 512x512 bf16 [N][K]
    u16*   wt_f1 = (u16*)(ws + 24248320);          // 6 x 2048x512 bf16 [N][K]
    u16*   wt_f2 = (u16*)(ws + 27394048);          // 6 x 512x2048 bf16 [N][K]
    u16*   ffh  = kb;                              // 4096x2048 bf16 (aliases kb)

    // ---- weight transpose+convert (once per launch) ----
    PtrArr<49> pdm;
    pdm.p[0] = W_in;
    for (int l = 0; l < NL; ++l) {
        const float* ws8[8] = { Wq1, Wk1, Wv1, Wo1, Wq2, Wk2, Wv2, Wo2 };
        for (int j = 0; j < 8; ++j) pdm.p[1 + l * 8 + j] = ws8[j] + (size_t)l * DM * DM;
    }
    PtrArr<6> pf1, pf2;
    for (int l = 0; l < NL; ++l) {
        pf1.p[l] = W_ff1 + (size_t)l * DM * DFF;
        pf2.p[l] = W_ff2 + (size_t)l * DFF * DM;
    }
    tr_kernel<49><<<dim3(8, 8, 49), 256, 0, stream>>>(pdm, wt_dm, 512, 512);
    tr_kernel<6><<<dim3(32, 8, 6), 256, 0, stream>>>(pf1, wt_f1, 512, 2048);
    tr_kernel<6><<<dim3(8, 32, 6), 256, 0, stream>>>(pf2, wt_f2, 2048, 512);

    const size_t WDM = (size_t)512 * 512;
    const size_t WFF = (size_t)512 * 2048;

    const dim3 gdm(8, 64);      // 64x64 tiles: M=4096,  N=512  -> 512 blocks
    const dim3 gqkv(24, 64);    // 64x64 tiles: M=4096,  N=1536 -> 1536 blocks
    const dim3 gq2kv(12, 128);  // 128x128:    M=16384, N=1536 -> 1536 blocks (q2 rides g0)
    const dim3 gf1(16, 32);     // 128x128:    M=4096,  N=2048 -> 512 blocks
    const dim3 gattn(BB * NH * (TD / 64));   // 1D, XCD-swizzled in-kernel

    cvt_kernel<<<8192, 256, 0, stream>>>(enc, encb, BB * TE * DM / 4);
    embed_kernel<<<4096, 256, 0, stream>>>(targets, emb, hb);
    gemm_bt<64, 64, false, false, false, false><<<gdm, 256, 0, stream>>>(
        hb, nullptr, nullptr, nullptr, 0, wt_dm, b_in, 0, nullptr, x, 4096, 512, 512);

    for (int l = 0; l < NL; ++l) {
        const size_t vo = (size_t)l * DM;
        const size_t fv = (size_t)l * DFF;
        const u16* tq1 = wt_dm + (1 + l * 8 + 0) * WDM;   // q1,k1,v1 contiguous [1536][512]
        const u16* to1 = wt_dm + (1 + l * 8 + 3) * WDM;
        const u16* tq2 = wt_dm + (1 + l * 8 + 4) * WDM;   // q2,k2,v2 contiguous [1536][512]
        const u16* to2 = wt_dm + (1 + l * 8 + 7) * WDM;
        const u16* tf1 = wt_f1 + l * WFF;
        const u16* tf2 = wt_f2 + l * WFF;
        const bool last = (l == NL - 1);

        {   // qkv1 with fused LN1 (all groups read LN(x))
            MGrp<3> mg;
            mg.A[0] = hb;  mg.A[1] = hb;  mg.A[2] = hb;   // unused (LNMODE=2)
            mg.out[0] = qb; mg.out[1] = kb; mg.out[2] = vb;
            mg.bias[0] = bq1 + vo; mg.bias[1] = bk1 + vo; mg.bias[2] = bv1 + vo;
            mg.mlim[0] = 4096; mg.mlim[1] = 4096; mg.mlim[2] = 4096;
            mg.skip[0] = 0; mg.skip[1] = 1; mg.skip[2] = 1;
            gemm_bt_multi<64, 64, 3, 2><<<gqkv, 256, 0, stream>>>(
                mg, x, ln1_g, ln1_b, vo, tq1, 512, tlen, 8);
        }
        fattn_mfma<<<gattn, 256, 0, stream>>>(qb, kb, vb, tlen, ctx, TD, TD, 1);
        gemm_bt<64, 64, false, false, true, false><<<gdm, 256, 0, stream>>>(
            ctx, nullptr, nullptr, nullptr, 0, to1, bo1, vo, x, x, 4096, 512, 512);

        {   // q2 (fused LN2, group 0) + k2/v2 (encb) in one launch
            MGrp<3> mg;
            mg.A[0] = hb;  mg.A[1] = encb; mg.A[2] = encb;
            mg.out[0] = qb; mg.out[1] = kb; mg.out[2] = vb;
            mg.bias[0] = bq2 + vo; mg.bias[1] = bk2 + vo; mg.bias[2] = bv2 + vo;
            mg.mlim[0] = 4096; mg.mlim[1] = 16384; mg.mlim[2] = 16384;
            mg.skip[0] = 0; mg.skip[1] = 1; mg.skip[2] = 1;
            gemm_bt_multi<128, 128, 3, 1><<<gq2kv, 256, 0, stream>>>(
                mg, x, ln2_g, ln2_b, vo, tq2, 512, elen, 10);
        }
        fattn_mfma<<<gattn, 256, 0, stream>>>(qb, kb, vb, elen, ctx, TD, TE, 0);
        gemm_bt<64, 64, false, false, true, false><<<gdm, 256, 0, stream>>>(
            ctx, nullptr, nullptr, nullptr, 0, to2, bo2, vo, x, x, 4096, 512, 512);

        // ff1 with fused LN3
        gemm_bt<128, 128, true, true, false, true><<<gf1, 256, 0, stream>>>(
            nullptr, x, ln3_g, ln3_b, vo, tf1, b_ff1, fv, nullptr, ffh, 4096, 2048, 512);
        // last layer: write final residual-add output directly to d_out (f32)
        gemm_bt<64, 64, false, false, true, false><<<gdm, 256, 0, stream>>>(
            ffh, nullptr, nullptr, nullptr, 0, tf2, b_ff2, vo, x,
            last ? (float*)d_out : x, 4096, 512, 2048);
    }
}

// Round 14
// 1265.557 us; speedup vs baseline: 1.2590x; 1.2590x over previous
//
#include <hip/hip_runtime.h>
#include <hip/hip_bf16.h>

#define BB   16
#define TD   256
#define TE   1024
#define DM   512
#define DFF  2048
#define NL   6
#define NH   8
#define DH   64

typedef unsigned short u16;
typedef unsigned int u32;
typedef short short8 __attribute__((ext_vector_type(8)));
typedef float f32x4 __attribute__((ext_vector_type(4)));

__device__ __forceinline__ float b2f(u16 u) {
    unsigned int x = ((unsigned int)u) << 16;
    float f;
    __builtin_memcpy(&f, &x, 4);
    return f;
}
__device__ __forceinline__ u16 f2b(float f) {           // round-to-nearest-even
    unsigned int x;
    __builtin_memcpy(&x, &f, 4);
    unsigned int r = x + 0x7fffu + ((x >> 16) & 1u);
    return (u16)(r >> 16);
}

// async global->LDS, 16B per lane, LDS dest = wave-uniform base + lane*16
__device__ __forceinline__ void gload_lds16(const u16* g, u16* l) {
    __builtin_amdgcn_global_load_lds(
        (const __attribute__((address_space(1))) unsigned int*)g,
        (__attribute__((address_space(3))) unsigned int*)l, 16, 0, 0);
}

// ---------------- f32 -> bf16 bulk convert (enc) ----------------
__global__ __launch_bounds__(256) void cvt_kernel(const float* __restrict__ in,
                                                  u16* __restrict__ out, int n4) {
    int i = blockIdx.x * 256 + threadIdx.x;
    if (i < n4) {
        float4 v = reinterpret_cast<const float4*>(in)[i];
        ushort4 o;
        o.x = f2b(v.x); o.y = f2b(v.y); o.z = f2b(v.z); o.w = f2b(v.w);
        reinterpret_cast<ushort4*>(out)[i] = o;
    }
}

// ---------------- weight transpose+convert: W[K][N] f32 -> Wt[N][K] bf16 -------
template <int NMAT>
struct PtrArr { const float* p[NMAT]; };

template <int NMAT>
__global__ __launch_bounds__(256) void tr_kernel(PtrArr<NMAT> P, u16* __restrict__ out,
                                                 int K, int N) {
    __shared__ u16 t[64][65];
    const float* W = P.p[blockIdx.z];
    u16* O = out + (size_t)blockIdx.z * K * N;
    int n0 = blockIdx.x * 64, k0 = blockIdx.y * 64;
    int tid = threadIdx.x;
    int r = tid >> 4, c = (tid & 15) * 4;
#pragma unroll
    for (int p = 0; p < 4; ++p) {
        int k = r + p * 16;
        float4 v = *reinterpret_cast<const float4*>(&W[(size_t)(k0 + k) * N + n0 + c]);
        t[c + 0][k] = f2b(v.x);
        t[c + 1][k] = f2b(v.y);
        t[c + 2][k] = f2b(v.z);
        t[c + 3][k] = f2b(v.w);
    }
    __syncthreads();
#pragma unroll
    for (int p = 0; p < 4; ++p) {
        int n = r + p * 16;
        ushort4 o;
        o.x = t[n][c]; o.y = t[n][c + 1]; o.z = t[n][c + 2]; o.w = t[n][c + 3];
        *reinterpret_cast<ushort4*>(&O[(size_t)(n0 + n) * K + k0 + c]) = o;
    }
}

// ---------------- embedding + sinusoidal PE -> bf16 ----------------
__global__ __launch_bounds__(256) void embed_kernel(const int* __restrict__ targets,
                                                    const float* __restrict__ emb,
                                                    u16* __restrict__ out) {
    int row = blockIdx.x;
    int t   = row & (TD - 1);
    int tgt = targets[row];
    const float c = -0.017988946039015984f;   // -ln(10000)/512
    for (int d = threadIdx.x; d < DM; d += 256) {
        float e   = emb[(size_t)tgt * DM + d] * 22.627416997969522f;  // sqrt(512)
        int   i2  = d & ~1;
        float div = expf(c * (float)i2);
        float arg = (float)t * div;
        float pe  = (d & 1) ? cosf(arg) : sinf(arg);
        out[(size_t)row * DM + d] = f2b(e + pe);
    }
}

// ---------------- layernorm: single-pass (E[x^2]-mean^2), float2 loads ----------
__global__ __launch_bounds__(256) void ln_kernel(const float* __restrict__ X,
                                                 const float* __restrict__ g,
                                                 const float* __restrict__ b,
                                                 size_t vo,
                                                 u16* __restrict__ O) {
    int row = blockIdx.x;
    int tid = threadIdx.x;
    float2 v = *reinterpret_cast<const float2*>(&X[(size_t)row * DM + 2 * tid]);
    float s  = v.x + v.y;
    float sq = v.x * v.x + v.y * v.y;
    __shared__ float red[8];
    int lane = tid & 63, wid = tid >> 6;
#pragma unroll
    for (int off = 32; off; off >>= 1) {
        s  += __shfl_xor(s, off);
        sq += __shfl_xor(sq, off);
    }
    if (lane == 0) { red[wid] = s; red[wid + 4] = sq; }
    __syncthreads();
    float mean = (red[0] + red[1] + red[2] + red[3]) * (1.0f / 512.0f);
    float ex2  = (red[4] + red[5] + red[6] + red[7]) * (1.0f / 512.0f);
    float var  = ex2 - mean * mean;
    float rs   = rsqrtf(var + 1e-5f);
    float o0 = (v.x - mean) * rs * g[vo + 2 * tid]     + b[vo + 2 * tid];
    float o1 = (v.y - mean) * rs * g[vo + 2 * tid + 1] + b[vo + 2 * tid + 1];
    u32 w = (u32)f2b(o0) | ((u32)f2b(o1) << 16);
    reinterpret_cast<u32*>(O)[(size_t)row * (DM / 2) + tid] = w;
}

// ---------------- 2-phase double-buffered GEMM ----------------
// C = act(A[MxK] @ Wt[NxK]^T + bias) (+resid). BK=32, LDS dbuf, prefetch-before-
// compute, ONE barrier per K-step (its implicit vmcnt(0) drains the prefetch).
template <int TM, int TN, bool OUTBF, bool RELU, bool RES>
__global__ __launch_bounds__(256) void gemm_bt(const u16* __restrict__ A,
                                               const u16* __restrict__ Bt,
                                               const float* __restrict__ bias, size_t bofs,
                                               const float* __restrict__ resid,
                                               void* __restrict__ C,
                                               int M, int N, int K) {
    __shared__ u16 As[2][TM * 32];
    __shared__ u16 Bs[2][TN * 32];
    int tid = threadIdx.x, wave = tid >> 6, lane = tid & 63;
    int col0 = blockIdx.x * TN, row0 = blockIdx.y * TM;
    constexpr int WM = TM / 2, WN = TN / 2;
    int wm = (wave >> 1) * WM, wn = (wave & 1) * WN;
    int lq = lane >> 4, lc = lane & 15;
    constexpr int NI = WM / 16, NJ = WN / 16;
    f32x4 acc[NI][NJ] = {};
    int srow = lane >> 2;          // 0..15 row within 16-row staging group
    int scol = (lane & 3) * 8;     // k element offset (8 bf16 = 16 B)

    auto stage = [&](int buf, int k0) {
#pragma unroll
        for (int s = 0; s < TM / 64; ++s) {
            int rbase = wave * (TM / 4) + s * 16;
            gload_lds16(A + (size_t)(row0 + rbase + srow) * K + k0 + scol, &As[buf][rbase * 32]);
        }
#pragma unroll
        for (int s = 0; s < TN / 64; ++s) {
            int rbase = wave * (TN / 4) + s * 16;
            gload_lds16(Bt + (size_t)(col0 + rbase + srow) * K + k0 + scol, &Bs[buf][rbase * 32]);
        }
    };

    stage(0, 0);
    __syncthreads();
    int cur = 0;
    for (int k0 = 0; k0 < K; k0 += 32) {
        if (k0 + 32 < K) stage(cur ^ 1, k0 + 32);   // prefetch next slice (async)
        short8 af[NI], bf[NJ];
#pragma unroll
        for (int i = 0; i < NI; ++i)
            af[i] = *reinterpret_cast<const short8*>(&As[cur][(wm + i * 16 + lc) * 32 + lq * 8]);
#pragma unroll
        for (int j = 0; j < NJ; ++j)
            bf[j] = *reinterpret_cast<const short8*>(&Bs[cur][(wn + j * 16 + lc) * 32 + lq * 8]);
#pragma unroll
        for (int i = 0; i < NI; ++i)
#pragma unroll
            for (int j = 0; j < NJ; ++j)
                acc[i][j] = __builtin_amdgcn_mfma_f32_16x16x32_bf16(af[i], bf[j], acc[i][j], 0, 0, 0);
        __syncthreads();           // waits vmcnt(0): prefetched tile landed
        cur ^= 1;
    }

    // epilogue: C/D layout col=lane&15, row=quad*4+reg
#pragma unroll
    for (int j = 0; j < NJ; ++j) {
        int n = col0 + wn + j * 16 + lc;
        float bv = bias[bofs + n];
#pragma unroll
        for (int i = 0; i < NI; ++i) {
#pragma unroll
            for (int r = 0; r < 4; ++r) {
                int m = row0 + wm + i * 16 + lq * 4 + r;
                float v = acc[i][j][r] + bv;
                if (RES)  v += resid[(size_t)m * N + n];
                if (RELU) v = fmaxf(v, 0.0f);
                if (OUTBF) ((u16*)C)[(size_t)m * N + n] = f2b(v);
                else       ((float*)C)[(size_t)m * N + n] = v;
            }
        }
    }
}

// ---------------- multi-group GEMM: concatenated-N weight, per-512-col group ----
// Each 512-col group g has its own A, output, bias, M-limit, and optional
// lens-based M-tile skip (rows batched 1<<rbShift; tiles past ceil64(lens[bb])
// are never read downstream -> block-uniform early-exit).
template <int NG>
struct MGrp {
    const u16* A[NG];
    u16* out[NG];
    const float* bias[NG];
    int mlim[NG];
    int skip[NG];
};

template <int TM, int TN, int NG>
__global__ __launch_bounds__(256) void gemm_bt_multi(MGrp<NG> mg,
                                                     const u16* __restrict__ Bt,
                                                     int K,
                                                     const int* __restrict__ lens,
                                                     int rbShift) {
    __shared__ u16 As[2][TM * 32];
    __shared__ u16 Bs[2][TN * 32];
    int tid = threadIdx.x, wave = tid >> 6, lane = tid & 63;
    int col0 = blockIdx.x * TN, row0 = blockIdx.y * TM;
    int g  = col0 >> 9;            // block-uniform group select (512 % TN == 0)
    int c0 = col0 & 511;

    if (row0 >= mg.mlim[g]) return;
    if (mg.skip[g]) {
        int bb  = row0 >> rbShift;
        int rl  = row0 & ((1 << rbShift) - 1);
        int lim = (lens[bb] + 63) & ~63;
        if (rl >= lim) return;       // block-uniform: no barrier divergence
    }
    const u16* A = mg.A[g];

    constexpr int WM = TM / 2, WN = TN / 2;
    int wm = (wave >> 1) * WM, wn = (wave & 1) * WN;
    int lq = lane >> 4, lc = lane & 15;
    constexpr int NI = WM / 16, NJ = WN / 16;
    f32x4 acc[NI][NJ] = {};
    int srow = lane >> 2;
    int scol = (lane & 3) * 8;

    auto stage = [&](int buf, int k0) {
#pragma unroll
        for (int s = 0; s < TM / 64; ++s) {
            int rbase = wave * (TM / 4) + s * 16;
            gload_lds16(A + (size_t)(row0 + rbase + srow) * K + k0 + scol, &As[buf][rbase * 32]);
        }
#pragma unroll
        for (int s = 0; s < TN / 64; ++s) {
            int rbase = wave * (TN / 4) + s * 16;
            gload_lds16(Bt + (size_t)(col0 + rbase + srow) * K + k0 + scol, &Bs[buf][rbase * 32]);
        }
    };

    stage(0, 0);
    __syncthreads();
    int cur = 0;
    for (int k0 = 0; k0 < K; k0 += 32) {
        if (k0 + 32 < K) stage(cur ^ 1, k0 + 32);
        short8 af[NI], bf[NJ];
#pragma unroll
        for (int i = 0; i < NI; ++i)
            af[i] = *reinterpret_cast<const short8*>(&As[cur][(wm + i * 16 + lc) * 32 + lq * 8]);
#pragma unroll
        for (int j = 0; j < NJ; ++j)
            bf[j] = *reinterpret_cast<const short8*>(&Bs[cur][(wn + j * 16 + lc) * 32 + lq * 8]);
#pragma unroll
        for (int i = 0; i < NI; ++i)
#pragma unroll
            for (int j = 0; j < NJ; ++j)
                acc[i][j] = __builtin_amdgcn_mfma_f32_16x16x32_bf16(af[i], bf[j], acc[i][j], 0, 0, 0);
        __syncthreads();
        cur ^= 1;
    }

    u16* O = mg.out[g];
    const float* bp = mg.bias[g];
#pragma unroll
    for (int j = 0; j < NJ; ++j) {
        int n = c0 + wn + j * 16 + lc;
        float bv = bp[n];
#pragma unroll
        for (int i = 0; i < NI; ++i) {
#pragma unroll
            for (int r = 0; r < 4; ++r) {
                int m = row0 + wm + i * 16 + lq * 4 + r;
                O[(size_t)m * 512 + n] = f2b(acc[i][j][r] + bv);
            }
        }
    }
}

// ---------------- MFMA flash attention: fixed-max softmax, dbuf K/V ------------
// QBLK=64, 256 thr. p = exp(s - 8) (scores bounded), row-sum via ones-fragment
// MFMA. V pair-packed u32 in [64][32] + XOR swizzle. K/V LDS double-buffered:
// one barrier per KV tile. Maskless fast path off-diagonal/pre-len. s_setprio(1)
// around MFMA clusters. 1D grid, XCD-aware contiguous-chunk swizzle.
#define QSTR 72

__device__ __forceinline__ int vidx(int d, int kp) {
    return d * 32 + (kp ^ (((d >> 2) & 7) << 2));
}

__global__ __launch_bounds__(256) void fattn_mfma(const u16* __restrict__ Q,
                                                  const u16* __restrict__ K,
                                                  const u16* __restrict__ V,
                                                  const int* __restrict__ lens,
                                                  u16* __restrict__ O,
                                                  int Tq, int Tk, int causal) {
    __shared__ u16 Qs[64 * QSTR];
    __shared__ u16 Ks[2][64 * QSTR];
    __shared__ u16 Ps[64 * QSTR];
    __shared__ u32 Vs32[2][64 * 32];
    int tid  = threadIdx.x;
    int wg      = blockIdx.x;
    int chunk   = gridDim.x >> 3;                 // gridDim.x % 8 == 0 (bijective)
    int logical = (wg & 7) * chunk + (wg >> 3);
    int nq   = Tq / 64;                           // 4
    int b    = logical / (NH * nq);
    int rem  = logical - b * (NH * nq);
    int h    = rem / nq;
    int qt0  = (rem - h * nq) * 64;
    int len  = lens[b];
    int wave = tid >> 6, lane = tid & 63;
    int lq = lane >> 4, lc = lane & 15;
    int sr = tid >> 4;          // 0..15
    int sd = (tid & 15) * 4;

    short8 bones;
    {
        u16 v = (lc == 0) ? (u16)0x3F80 : (u16)0;
        u16 tmp[8] = { v, v, v, v, v, v, v, v };
        __builtin_memcpy(&bones, tmp, 16);
    }

    // Q tile load + scale (1/8 = 1/sqrt(dh))
#pragma unroll
    for (int i = 0; i < 4; ++i) {
        int q = sr + i * 16;
        ushort4 v = *reinterpret_cast<const ushort4*>(
            &Q[(size_t)(b * Tq + qt0 + q) * DM + h * DH + sd]);
        ushort4 w;
        w.x = f2b(b2f(v.x) * 0.125f); w.y = f2b(b2f(v.y) * 0.125f);
        w.z = f2b(b2f(v.z) * 0.125f); w.w = f2b(b2f(v.w) * 0.125f);
        *reinterpret_cast<ushort4*>(&Qs[q * QSTR + sd]) = w;
    }

    // K tile rows; V pair rows -> buf 0
    ushort4 kr[4], vr[2][2];
#pragma unroll
    for (int i = 0; i < 4; ++i) {
        int k = sr + i * 16;
        kr[i] = *reinterpret_cast<const ushort4*>(&K[(size_t)(b * Tk + k) * DM + h * DH + sd]);
    }
#pragma unroll
    for (int i = 0; i < 2; ++i) {
        int kp = sr + i * 16;
#pragma unroll
        for (int p = 0; p < 2; ++p)
            vr[i][p] = *reinterpret_cast<const ushort4*>(
                &V[(size_t)(b * Tk + 2 * kp + p) * DM + h * DH + sd]);
    }
#pragma unroll
    for (int i = 0; i < 4; ++i) {
        int k = sr + i * 16;
        *reinterpret_cast<ushort4*>(&Ks[0][k * QSTR + sd]) = kr[i];
    }
#pragma unroll
    for (int i = 0; i < 2; ++i) {
        int kp = sr + i * 16;
        u16 a0[4], a1[4];
        __builtin_memcpy(a0, &vr[i][0], 8);
        __builtin_memcpy(a1, &vr[i][1], 8);
#pragma unroll
        for (int j = 0; j < 4; ++j)
            Vs32[0][vidx(sd + j, kp)] = (u32)a0[j] | ((u32)a1[j] << 16);
    }
    __syncthreads();

    short8 aq0 = *reinterpret_cast<const short8*>(&Qs[(wave * 16 + lc) * QSTR + lq * 8]);
    short8 aq1 = *reinterpret_cast<const short8*>(&Qs[(wave * 16 + lc) * QSTR + 32 + lq * 8]);

    f32x4 Ow[4] = {};
    f32x4 Ol = {};

    int kend = causal ? min(len, qt0 + 64) : len;
    int cur = 0;
    for (int kt0 = 0; kt0 < kend; kt0 += 64) {
        bool more = (kt0 + 64) < kend;
        if (more) {
#pragma unroll
            for (int i = 0; i < 4; ++i) {
                int k = kt0 + 64 + sr + i * 16;
                kr[i] = *reinterpret_cast<const ushort4*>(
                    &K[(size_t)(b * Tk + k) * DM + h * DH + sd]);
            }
#pragma unroll
            for (int i = 0; i < 2; ++i) {
                int kp = sr + i * 16;
#pragma unroll
                for (int p = 0; p < 2; ++p)
                    vr[i][p] = *reinterpret_cast<const ushort4*>(
                        &V[(size_t)(b * Tk + kt0 + 64 + 2 * kp + p) * DM + h * DH + sd]);
            }
        }

        f32x4 sa[4] = {};
        __builtin_amdgcn_s_setprio(1);
#pragma unroll
        for (int n = 0; n < 4; ++n) {
            short8 bk0 = *reinterpret_cast<const short8*>(&Ks[cur][(n * 16 + lc) * QSTR + lq * 8]);
            short8 bk1 = *reinterpret_cast<const short8*>(&Ks[cur][(n * 16 + lc) * QSTR + 32 + lq * 8]);
            sa[n] = __builtin_amdgcn_mfma_f32_16x16x32_bf16(aq0, bk0, sa[n], 0, 0, 0);
            sa[n] = __builtin_amdgcn_mfma_f32_16x16x32_bf16(aq1, bk1, sa[n], 0, 0, 0);
        }
        __builtin_amdgcn_s_setprio(0);

        int qrow_base = qt0 + wave * 16 + lq * 4;
        bool nomask = (kt0 + 64 <= len) &&
                      (!causal || (kt0 + 63 <= qt0 + wave * 16));
        if (nomask) {
#pragma unroll
            for (int r = 0; r < 4; ++r)
#pragma unroll
                for (int n = 0; n < 4; ++n)
                    Ps[(wave * 16 + lq * 4 + r) * QSTR + n * 16 + lc] =
                        f2b(__expf(sa[n][r] - 8.0f));
        } else {
#pragma unroll
            for (int r = 0; r < 4; ++r) {
                int qrow = qrow_base + r;
#pragma unroll
                for (int n = 0; n < 4; ++n) {
                    int key = kt0 + n * 16 + lc;
                    bool inv = (key >= len) || (causal && key > qrow);
                    float p = inv ? 0.0f : __expf(sa[n][r] - 8.0f);
                    Ps[(wave * 16 + lq * 4 + r) * QSTR + n * 16 + lc] = f2b(p);
                }
            }
        }
        // no barrier: Ps rows [wave*16, wave*16+16) are wave-private

        short8 ap0 = *reinterpret_cast<const short8*>(&Ps[(wave * 16 + lc) * QSTR + lq * 8]);
        short8 ap1 = *reinterpret_cast<const short8*>(&Ps[(wave * 16 + lc) * QSTR + 32 + lq * 8]);
        __builtin_amdgcn_s_setprio(1);
#pragma unroll
        for (int n = 0; n < 4; ++n) {
            int d = n * 16 + lc;
#pragma unroll
            for (int ks = 0; ks < 2; ++ks) {
                int base = d * 32 + ((ks * 16 + lq * 4) ^ (((d >> 2) & 7) << 2));
                uint4 vv = *reinterpret_cast<const uint4*>(&Vs32[cur][base]);   // b128
                short8 bv;
                __builtin_memcpy(&bv, &vv, 16);
                Ow[n] = __builtin_amdgcn_mfma_f32_16x16x32_bf16(ks ? ap1 : ap0, bv, Ow[n], 0, 0, 0);
            }
        }
        Ol = __builtin_amdgcn_mfma_f32_16x16x32_bf16(ap0, bones, Ol, 0, 0, 0);
        Ol = __builtin_amdgcn_mfma_f32_16x16x32_bf16(ap1, bones, Ol, 0, 0, 0);
        __builtin_amdgcn_s_setprio(0);

        if (more) {
#pragma unroll
            for (int i = 0; i < 4; ++i) {
                int k = sr + i * 16;
                *reinterpret_cast<ushort4*>(&Ks[cur ^ 1][k * QSTR + sd]) = kr[i];
            }
#pragma unroll
            for (int i = 0; i < 2; ++i) {
                int kp = sr + i * 16;
                u16 a0[4], a1[4];
                __builtin_memcpy(a0, &vr[i][0], 8);
                __builtin_memcpy(a1, &vr[i][1], 8);
#pragma unroll
                for (int j = 0; j < 4; ++j)
                    Vs32[cur ^ 1][vidx(sd + j, kp)] = (u32)a0[j] | ((u32)a1[j] << 16);
            }
            __syncthreads();
            cur ^= 1;
        }
    }

#pragma unroll
    for (int r = 0; r < 4; ++r) {
        float lsum = __shfl(Ol[r], lane & 48);   // from lane lq*16 (lc==0)
        float inv = 1.0f / lsum;
        size_t rowoff = (size_t)(b * Tq + qt0 + wave * 16 + lq * 4 + r) * DM + h * DH;
#pragma unroll
        for (int n = 0; n < 4; ++n)
            O[rowoff + n * 16 + lc] = f2b(Ow[n][r] * inv);
    }
}

extern "C" void kernel_launch(void* const* d_in, const int* in_sizes, int n_in,
                              void* d_out, int out_size, void* d_ws, size_t ws_size,
                              hipStream_t stream) {
    const int*   targets = (const int*)d_in[0];
    const int*   tlen    = (const int*)d_in[1];
    const float* enc     = (const float*)d_in[2];
    const int*   elen    = (const int*)d_in[3];
    const float* emb     = (const float*)d_in[4];
    const float* W_in    = (const float*)d_in[5];
    const float* b_in    = (const float*)d_in[6];
    const float* ln1_g   = (const float*)d_in[7];
    const float* ln1_b   = (const float*)d_in[8];
    const float* Wq1 = (const float*)d_in[9],  *bq1 = (const float*)d_in[10];
    const float* Wk1 = (const float*)d_in[11], *bk1 = (const float*)d_in[12];
    const float* Wv1 = (const float*)d_in[13], *bv1 = (const float*)d_in[14];
    const float* Wo1 = (const float*)d_in[15], *bo1 = (const float*)d_in[16];
    const float* ln2_g = (const float*)d_in[17], *ln2_b = (const float*)d_in[18];
    const float* Wq2 = (const float*)d_in[19], *bq2 = (const float*)d_in[20];
    const float* Wk2 = (const float*)d_in[21], *bk2 = (const float*)d_in[22];
    const float* Wv2 = (const float*)d_in[23], *bv2 = (const float*)d_in[24];
    const float* Wo2 = (const float*)d_in[25], *bo2 = (const float*)d_in[26];
    const float* ln3_g = (const float*)d_in[27], *ln3_b = (const float*)d_in[28];
    const float* W_ff1 = (const float*)d_in[29], *b_ff1 = (const float*)d_in[30];
    const float* W_ff2 = (const float*)d_in[31], *b_ff2 = (const float*)d_in[32];

    float* ws   = (float*)d_ws;
    float* x    = ws;                              // 4096x512 f32
    u16*   hb   = (u16*)(ws + 2097152);            // 4096x512 bf16
    u16*   qb   = (u16*)(ws + 3145728);            // 4096x512 bf16
    u16*   ctx  = (u16*)(ws + 4194304);            // 4096x512 bf16
    u16*   kb   = (u16*)(ws + 5242880);            // 16384x512 bf16
    u16*   vb   = (u16*)(ws + 9437184);            // 16384x512 bf16
    u16*   encb = (u16*)(ws + 13631488);           // 16384x512 bf16
    u16*   wt_dm = (u16*)(ws + 17825792);          // 49 x 512x512 bf16 [N][K]
    u16*   wt_f1 = (u16*)(ws + 24248320);          // 6 x 2048x512 bf16 [N][K]
    u16*   wt_f2 = (u16*)(ws + 27394048);          // 6 x 512x2048 bf16 [N][K]
    u16*   ffh  = kb;                              // 4096x2048 bf16 (aliases kb)

    // ---- weight transpose+convert (once per launch) ----
    PtrArr<49> pdm;
    pdm.p[0] = W_in;
    for (int l = 0; l < NL; ++l) {
        const float* ws8[8] = { Wq1, Wk1, Wv1, Wo1, Wq2, Wk2, Wv2, Wo2 };
        for (int j = 0; j < 8; ++j) pdm.p[1 + l * 8 + j] = ws8[j] + (size_t)l * DM * DM;
    }
    PtrArr<6> pf1, pf2;
    for (int l = 0; l < NL; ++l) {
        pf1.p[l] = W_ff1 + (size_t)l * DM * DFF;
        pf2.p[l] = W_ff2 + (size_t)l * DFF * DM;
    }
    tr_kernel<49><<<dim3(8, 8, 49), 256, 0, stream>>>(pdm, wt_dm, 512, 512);
    tr_kernel<6><<<dim3(32, 8, 6), 256, 0, stream>>>(pf1, wt_f1, 512, 2048);
    tr_kernel<6><<<dim3(8, 32, 6), 256, 0, stream>>>(pf2, wt_f2, 2048, 512);

    const size_t WDM = (size_t)512 * 512;
    const size_t WFF = (size_t)512 * 2048;

    const dim3 gdm(8, 64);      // 64x64 tiles: M=4096,  N=512  -> 512 blocks
    const dim3 gqkv(24, 64);    // 64x64 tiles: M=4096,  N=1536 -> 1536 blocks
    const dim3 gq2kv(12, 128);  // 128x128:    M=16384, N=1536 -> 1536 blocks (q2 rides g0)
    const dim3 gf1(16, 32);     // 128x128:    M=4096,  N=2048 -> 512 blocks
    const dim3 gattn(BB * NH * (TD / 64));   // 1D, XCD-swizzled in-kernel (512 % 8 == 0)

    cvt_kernel<<<8192, 256, 0, stream>>>(enc, encb, BB * TE * DM / 4);
    embed_kernel<<<4096, 256, 0, stream>>>(targets, emb, hb);
    gemm_bt<64, 64, false, false, false><<<gdm, 256, 0, stream>>>(hb, wt_dm, b_in, 0, nullptr, x, 4096, 512, 512);

    for (int l = 0; l < NL; ++l) {
        const size_t vo = (size_t)l * DM;
        const size_t fv = (size_t)l * DFF;
        const u16* tq1 = wt_dm + (1 + l * 8 + 0) * WDM;   // q1,k1,v1 contiguous [1536][512]
        const u16* to1 = wt_dm + (1 + l * 8 + 3) * WDM;
        const u16* tq2 = wt_dm + (1 + l * 8 + 4) * WDM;   // q2,k2,v2 contiguous [1536][512]
        const u16* to2 = wt_dm + (1 + l * 8 + 7) * WDM;
        const u16* tf1 = wt_f1 + l * WFF;
        const u16* tf2 = wt_f2 + l * WFF;
        const bool last = (l == NL - 1);

        ln_kernel<<<4096, 256, 0, stream>>>(x, ln1_g, ln1_b, vo, hb);
        {
            MGrp<3> mg;
            mg.A[0] = hb;  mg.A[1] = hb;  mg.A[2] = hb;
            mg.out[0] = qb; mg.out[1] = kb; mg.out[2] = vb;
            mg.bias[0] = bq1 + vo; mg.bias[1] = bk1 + vo; mg.bias[2] = bv1 + vo;
            mg.mlim[0] = 4096; mg.mlim[1] = 4096; mg.mlim[2] = 4096;
            mg.skip[0] = 0; mg.skip[1] = 1; mg.skip[2] = 1;   // K/V rows >= ceil64(tlen) dead
            gemm_bt_multi<64, 64, 3><<<gqkv, 256, 0, stream>>>(mg, tq1, 512, tlen, 8);
        }
        fattn_mfma<<<gattn, 256, 0, stream>>>(qb, kb, vb, tlen, ctx, TD, TD, 1);
        gemm_bt<64, 64, false, false, true><<<gdm, 256, 0, stream>>>(ctx, to1, bo1, vo, x, x, 4096, 512, 512);

        ln_kernel<<<4096, 256, 0, stream>>>(x, ln2_g, ln2_b, vo, hb);
        {
            MGrp<3> mg;
            mg.A[0] = hb;  mg.A[1] = encb; mg.A[2] = encb;
            mg.out[0] = qb; mg.out[1] = kb; mg.out[2] = vb;
            mg.bias[0] = bq2 + vo; mg.bias[1] = bk2 + vo; mg.bias[2] = bv2 + vo;
            mg.mlim[0] = 4096; mg.mlim[1] = 16384; mg.mlim[2] = 16384;
            mg.skip[0] = 0; mg.skip[1] = 1; mg.skip[2] = 1;   // K/V rows >= ceil64(elen) dead
            gemm_bt_multi<128, 128, 3><<<gq2kv, 256, 0, stream>>>(mg, tq2, 512, elen, 10);
        }
        fattn_mfma<<<gattn, 256, 0, stream>>>(qb, kb, vb, elen, ctx, TD, TE, 0);
        gemm_bt<64, 64, false, false, true><<<gdm, 256, 0, stream>>>(ctx, to2, bo2, vo, x, x, 4096, 512, 512);

        ln_kernel<<<4096, 256, 0, stream>>>(x, ln3_g, ln3_b, vo, hb);
        gemm_bt<128, 128, true, true, false><<<gf1, 256, 0, stream>>>(hb, tf1, b_ff1, fv, nullptr, ffh, 4096, 2048, 512);
        // last layer: write final residual-add output directly to d_out (f32)
        gemm_bt<64, 64, false, false, true><<<gdm, 256, 0, stream>>>(
            ffh, tf2, b_ff2, vo, x, last ? (float*)d_out : x, 4096, 512, 2048);
    }
}